// Round 14
// baseline (2581.172 us; speedup 1.0000x reference)
//
#include <hip/hip_runtime.h>

// Group_10: replicate-pad 3x3 conv (4,512,32,32)->(4,9728,32,32) + bias,
// then faithful-PS reinterpretation to (4,152,256,256).
//
// Round 14: R12 loop byte-identical (best: 392us, MfmaUtil 44.4) + two
// scheduling-only changes:
//  (a) block mapping for B reuse: per XCD only 2 mb values (A panels pinned
//      in XCD L2); 16 blocks sharing an nb B-panel are temporally adjacent
//      (bids 16j..16j+15) -> B fetched from HBM ~once. FETCH 740->~300MB.
//  (b) launch_bounds(256,3): allow 3 blocks/CU (LDS 144<=160KB, VGPR 128).

#define CIN   512
#define COUT  9728
#define NBAT  4
#define KTOT  4608
#define KSTEPS 72           // K = 72 * 64
#define TB     16384        // packed tile: 128 rows x 64 bf16 x 2B
#define PANEL  (KSTEPS * TB)

typedef __bf16 bf16x8 __attribute__((ext_vector_type(8)));
typedef float  f32x4  __attribute__((ext_vector_type(4)));

#define SCHED0() __builtin_amdgcn_sched_barrier(0)
#define PRIO1() __builtin_amdgcn_s_setprio(1)
#define PRIO0() __builtin_amdgcn_s_setprio(0)

// ---------------- fallback: direct conv (correct, slow) ----------------
__global__ __launch_bounds__(256) void conv_ps_direct(
    const float* __restrict__ x, const float* __restrict__ Wt,
    const float* __restrict__ bias, float* __restrict__ out)
{
    int flat = blockIdx.x * 256 + threadIdx.x;
    int w  = flat & 31;
    int h  = (flat >> 5) & 31;
    int t  = flat >> 10;
    int co = t % COUT;
    int b  = t / COUT;

    const float* xb = x + (size_t)b * CIN * 1024;
    const float* Wc = Wt + (size_t)co * CIN * 9;

    int hm = h > 0  ? h - 1 : 0;
    int hp = h < 31 ? h + 1 : 31;
    int wm = w > 0  ? w - 1 : 0;
    int wp = w < 31 ? w + 1 : 31;

    float acc = bias[co];
    #pragma unroll 4
    for (int ci = 0; ci < CIN; ++ci) {
        const float* xc = xb + ci * 1024;
        const float* wf = Wc + ci * 9;
        const float* r0 = xc + hm * 32;
        const float* r1 = xc + h  * 32;
        const float* r2 = xc + hp * 32;
        acc += wf[0] * r0[wm] + wf[1] * r0[w] + wf[2] * r0[wp];
        acc += wf[3] * r1[wm] + wf[4] * r1[w] + wf[5] * r1[wp];
        acc += wf[6] * r2[wm] + wf[7] * r2[w] + wf[8] * r2[wp];
    }
    int cc = co & 63;
    int n  = co >> 6;
    int i  = ((cc >> 1) << 3) | (w & 7);
    int j  = ((cc & 1) << 7) | ((h >> 1) << 3) | ((h & 1) << 2) | (w >> 3);
    out[(((size_t)b * 152 + n) * 256 + i) * 256 + j] = acc;
}

// -------- pack W: fp32 -> bf16, tiled + XOR-swizzled (R3, verified) --------
__global__ __launch_bounds__(256) void pack_W(const float* __restrict__ Wt,
                                              __bf16* __restrict__ Wws)
{
    int G = blockIdx.x * 256 + threadIdx.x;   // < 76*72*128*8
    int s    = G & 7;
    int r    = (G >> 3) & 127;
    int rest = G >> 10;                        // nb*72 + kt
    int kt = rest % KSTEPS;
    int nb = rest / KSTEPS;
    int n  = nb * 128 + r;
    int g  = s ^ (r & 7);
    int k0 = kt * 64 + g * 8;

    const float* src = Wt + (size_t)n * KTOT + k0;
    float4 v0 = *(const float4*)(src);
    float4 v1 = *(const float4*)(src + 4);
    bf16x8 o;
    o[0] = (__bf16)v0.x; o[1] = (__bf16)v0.y; o[2] = (__bf16)v0.z; o[3] = (__bf16)v0.w;
    o[4] = (__bf16)v1.x; o[5] = (__bf16)v1.y; o[6] = (__bf16)v1.z; o[7] = (__bf16)v1.w;
    *(bf16x8*)(Wws + (size_t)G * 8) = o;
}

// -------- pack A: im2col bf16, same tiling/swizzle (R3, verified) --------
__global__ __launch_bounds__(256) void pack_A(const float* __restrict__ x,
                                              __bf16* __restrict__ Aws)
{
    int G = blockIdx.x * 256 + threadIdx.x;   // < 32*72*128*8
    int s    = G & 7;
    int r    = (G >> 3) & 127;
    int rest = G >> 10;                        // mb*72 + kt
    int kt = rest % KSTEPS;
    int mb = rest / KSTEPS;
    int m  = mb * 128 + r;
    int b  = m >> 10;
    int h  = (m >> 5) & 31;
    int w  = m & 31;
    int g  = s ^ (r & 7);
    int k0 = kt * 64 + g * 8;

    const float* xb = x + (size_t)b * CIN * 1024;
    bf16x8 o;
    #pragma unroll
    for (int e = 0; e < 8; ++e) {
        int k  = k0 + e;
        int ci = k / 9;
        int r9 = k - ci * 9;
        int kh = r9 / 3;
        int kw = r9 - kh * 3;
        int hh = h + kh - 1; hh = hh < 0 ? 0 : (hh > 31 ? 31 : hh);
        int ww = w + kw - 1; ww = ww < 0 ? 0 : (ww > 31 ? 31 : ww);
        o[e] = (__bf16)xb[(ci << 10) + (hh << 5) + ww];
    }
    *(bf16x8*)(Aws + (size_t)G * 8) = o;
}

// ---- 256x128 GEMM: 4 waves of 128x64, read-first/stage-late, fused PS ----
__global__ __launch_bounds__(256, 3) void gemm_ps(
    const __bf16* __restrict__ Aws, const __bf16* __restrict__ Wws,
    const float* __restrict__ bias, float* __restrict__ out)
{
    __shared__ __align__(16) char smem[49152];  // A0:[0,16K) A1:[16K,32K) B:[32K,48K)

    // B-reuse mapping: 1216 blocks = 8 XCD * 152. Per XCD: mb in {xcd*2,
    // xcd*2+1} (A panels pinned in XCD L2); nb = slow -> bids 16j..16j+15
    // share nb's B panel, temporally adjacent across XCDs.
    int bid = blockIdx.x;
    int gl  = bid >> 3;               // 0..151 within XCD
    int mb  = (bid & 7) * 2 + (gl & 1);
    int nb  = gl >> 1;                // 0..75

    int t    = threadIdx.x;
    int lane = t & 63;
    int wid  = t >> 6;
    int wm = wid >> 1, wn = wid & 1;       // 2x2 waves; wave tile 128x64

    const char* A0 = (const char*)Aws + (size_t)(mb * 2 + 0) * PANEL;
    const char* A1 = (const char*)Aws + (size_t)(mb * 2 + 1) * PANEL;
    const char* Bb = (const char*)Wws + (size_t)nb * PANEL;

    f32x4 acc[8][4] = {};
    bf16x8 af[8][2], bf[4][2];

    int rb   = lane & 15;
    int gsel = lane >> 4;      // 0..3
    int x7   = lane & 7;
    int apanel = wm << 14;     // wm*16384
    int kx0 = ((gsel    ) ^ x7) << 4;
    int kx1 = ((gsel + 4) ^ x7) << 4;

    auto stage_tile = [&](int kt) {
        const char* As0 = A0 + (size_t)kt * TB;
        const char* As1 = A1 + (size_t)kt * TB;
        const char* Bs  = Bb + (size_t)kt * TB;
        #pragma unroll
        for (int i = 0; i < 4; ++i) {
            int G16 = (i * 256 + t) * 16;
            __builtin_amdgcn_global_load_lds(
                (const __attribute__((address_space(1))) void*)(As0 + G16),
                (__attribute__((address_space(3))) void*)(smem + G16), 16, 0, 0);
            __builtin_amdgcn_global_load_lds(
                (const __attribute__((address_space(1))) void*)(As1 + G16),
                (__attribute__((address_space(3))) void*)(smem + 16384 + G16), 16, 0, 0);
            __builtin_amdgcn_global_load_lds(
                (const __attribute__((address_space(1))) void*)(Bs + G16),
                (__attribute__((address_space(3))) void*)(smem + 32768 + G16), 16, 0, 0);
        }
    };

    // prologue: stage tile 0, drain, barrier
    stage_tile(0);
    __syncthreads();     // vmcnt(0)+lgkmcnt(0) drain + barrier: tile 0 resident

    for (int kt = 0; kt < KSTEPS; ++kt) {
        int kt1 = kt + 1 < KSTEPS ? kt + 1 : KSTEPS - 1;  // harmless re-stage

        // ---- read ALL of tile kt's fragments into registers ----
        #pragma unroll
        for (int mi = 0; mi < 8; ++mi) {
            af[mi][0] = *(const bf16x8*)(smem + apanel + (mi * 16 + rb) * 128 + kx0);
            af[mi][1] = *(const bf16x8*)(smem + apanel + (mi * 16 + rb) * 128 + kx1);
        }
        #pragma unroll
        for (int ni = 0; ni < 4; ++ni) {
            bf[ni][0] = *(const bf16x8*)(smem + 32768 + ((wn * 64) + ni * 16 + rb) * 128 + kx0);
            bf[ni][1] = *(const bf16x8*)(smem + 32768 + ((wn * 64) + ni * 16 + rb) * 128 + kx1);
        }
        __syncthreads();   // lgkm drain (reads retired block-wide); vmcnt already 0

        // ---- stage tile kt+1 (overwrites buffer; safe now) ----
        stage_tile(kt1);
        SCHED0();          // pin: stage issue precedes MFMA cluster

        // ---- MFMA on registers; covers the staging latency ----
        PRIO1();
        #pragma unroll
        for (int mi = 0; mi < 8; ++mi)
            #pragma unroll
            for (int ni = 0; ni < 4; ++ni)
                acc[mi][ni] = __builtin_amdgcn_mfma_f32_16x16x32_bf16(
                    af[mi][0], bf[ni][0], acc[mi][ni], 0, 0, 0);
        #pragma unroll
        for (int mi = 0; mi < 8; ++mi)
            #pragma unroll
            for (int ni = 0; ni < 4; ++ni)
                acc[mi][ni] = __builtin_amdgcn_mfma_f32_16x16x32_bf16(
                    af[mi][1], bf[ni][1], acc[mi][ni], 0, 0, 0);
        PRIO0();

        __syncthreads();   // vmcnt(0) drain AFTER MFMA cover
    }

    // epilogue: bias + phase-shift scatter (R3/R10/R12-verified)
    int M0 = mb * 256 + wm * 128;
    int N0 = nb * 128 + wn * 64;
    int nlane = lane & 15;
    int mrow  = (lane >> 4) * 4;

    #pragma unroll
    for (int ni = 0; ni < 4; ++ni) {
        int n  = N0 + ni * 16 + nlane;
        float bv = bias[n];
        int cc  = n & 63;
        int nch = n >> 6;
        int i_hi = (cc >> 1) << 3;
        int j_hi = (cc & 1) << 7;
        #pragma unroll
        for (int mi = 0; mi < 8; ++mi) {
            #pragma unroll
            for (int r = 0; r < 4; ++r) {
                int m = M0 + mi * 16 + mrow + r;
                int b = m >> 10, h = (m >> 5) & 31, w = m & 31;
                int i = i_hi | (w & 7);
                int j = j_hi | ((h >> 1) << 3) | ((h & 1) << 2) | (w >> 3);
                out[((size_t)b * 152 + nch) * 65536 + i * 256 + j] =
                    acc[mi][ni][r] + bv;
            }
        }
    }
}

extern "C" void kernel_launch(void* const* d_in, const int* in_sizes, int n_in,
                              void* d_out, int out_size, void* d_ws, size_t ws_size,
                              hipStream_t stream) {
    const float* x    = (const float*)d_in[0];
    const float* Wt   = (const float*)d_in[1];
    const float* bias = (const float*)d_in[2];
    float* out        = (float*)d_out;

    const size_t needW = (size_t)76 * PANEL;  // 89,653,248
    const size_t needA = (size_t)32 * PANEL;  // 37,748,736

    if (ws_size >= needW + needA) {
        __bf16* Wws = (__bf16*)d_ws;
        __bf16* Aws = (__bf16*)((char*)d_ws + needW);
        pack_W<<<21888, 256, 0, stream>>>(Wt, Wws);
        pack_A<<<9216, 256, 0, stream>>>(x, Aws);
        gemm_ps<<<16 * 76, 256, 0, stream>>>(Aws, Wws, bias, out);
    } else {
        const int total = NBAT * COUT * 1024;
        conv_ps_direct<<<total / 256, 256, 0, stream>>>(x, Wt, bias, out);
    }
}

// Round 15
// 458.058 us; speedup vs baseline: 5.6350x; 5.6350x over previous
//
#include <hip/hip_runtime.h>

// Group_10: replicate-pad 3x3 conv (4,512,32,32)->(4,9728,32,32) + bias,
// then faithful-PS reinterpretation to (4,152,256,256).
//
// Round 15: R12 EXACT loop + launch_bounds(256,2) (R14's (256,3) forced an
// accumulator spill: VGPR 128->84, scratch traffic 6.8GB WRITE — reverted).
// Keeps only R14's scheduling-safe change: B-reuse block mapping (per XCD
// 2 mb values -> A pinned in XCD L2; 16 temporally-adjacent blocks share
// each nb B-panel -> B fetched from HBM ~once).

#define CIN   512
#define COUT  9728
#define NBAT  4
#define KTOT  4608
#define KSTEPS 72           // K = 72 * 64
#define TB     16384        // packed tile: 128 rows x 64 bf16 x 2B
#define PANEL  (KSTEPS * TB)

typedef __bf16 bf16x8 __attribute__((ext_vector_type(8)));
typedef float  f32x4  __attribute__((ext_vector_type(4)));

#define SCHED0() __builtin_amdgcn_sched_barrier(0)
#define PRIO1() __builtin_amdgcn_s_setprio(1)
#define PRIO0() __builtin_amdgcn_s_setprio(0)

// ---------------- fallback: direct conv (correct, slow) ----------------
__global__ __launch_bounds__(256) void conv_ps_direct(
    const float* __restrict__ x, const float* __restrict__ Wt,
    const float* __restrict__ bias, float* __restrict__ out)
{
    int flat = blockIdx.x * 256 + threadIdx.x;
    int w  = flat & 31;
    int h  = (flat >> 5) & 31;
    int t  = flat >> 10;
    int co = t % COUT;
    int b  = t / COUT;

    const float* xb = x + (size_t)b * CIN * 1024;
    const float* Wc = Wt + (size_t)co * CIN * 9;

    int hm = h > 0  ? h - 1 : 0;
    int hp = h < 31 ? h + 1 : 31;
    int wm = w > 0  ? w - 1 : 0;
    int wp = w < 31 ? w + 1 : 31;

    float acc = bias[co];
    #pragma unroll 4
    for (int ci = 0; ci < CIN; ++ci) {
        const float* xc = xb + ci * 1024;
        const float* wf = Wc + ci * 9;
        const float* r0 = xc + hm * 32;
        const float* r1 = xc + h  * 32;
        const float* r2 = xc + hp * 32;
        acc += wf[0] * r0[wm] + wf[1] * r0[w] + wf[2] * r0[wp];
        acc += wf[3] * r1[wm] + wf[4] * r1[w] + wf[5] * r1[wp];
        acc += wf[6] * r2[wm] + wf[7] * r2[w] + wf[8] * r2[wp];
    }
    int cc = co & 63;
    int n  = co >> 6;
    int i  = ((cc >> 1) << 3) | (w & 7);
    int j  = ((cc & 1) << 7) | ((h >> 1) << 3) | ((h & 1) << 2) | (w >> 3);
    out[(((size_t)b * 152 + n) * 256 + i) * 256 + j] = acc;
}

// -------- pack W: fp32 -> bf16, tiled + XOR-swizzled (R3, verified) --------
__global__ __launch_bounds__(256) void pack_W(const float* __restrict__ Wt,
                                              __bf16* __restrict__ Wws)
{
    int G = blockIdx.x * 256 + threadIdx.x;   // < 76*72*128*8
    int s    = G & 7;
    int r    = (G >> 3) & 127;
    int rest = G >> 10;                        // nb*72 + kt
    int kt = rest % KSTEPS;
    int nb = rest / KSTEPS;
    int n  = nb * 128 + r;
    int g  = s ^ (r & 7);
    int k0 = kt * 64 + g * 8;

    const float* src = Wt + (size_t)n * KTOT + k0;
    float4 v0 = *(const float4*)(src);
    float4 v1 = *(const float4*)(src + 4);
    bf16x8 o;
    o[0] = (__bf16)v0.x; o[1] = (__bf16)v0.y; o[2] = (__bf16)v0.z; o[3] = (__bf16)v0.w;
    o[4] = (__bf16)v1.x; o[5] = (__bf16)v1.y; o[6] = (__bf16)v1.z; o[7] = (__bf16)v1.w;
    *(bf16x8*)(Wws + (size_t)G * 8) = o;
}

// -------- pack A: im2col bf16, same tiling/swizzle (R3, verified) --------
__global__ __launch_bounds__(256) void pack_A(const float* __restrict__ x,
                                              __bf16* __restrict__ Aws)
{
    int G = blockIdx.x * 256 + threadIdx.x;   // < 32*72*128*8
    int s    = G & 7;
    int r    = (G >> 3) & 127;
    int rest = G >> 10;                        // mb*72 + kt
    int kt = rest % KSTEPS;
    int mb = rest / KSTEPS;
    int m  = mb * 128 + r;
    int b  = m >> 10;
    int h  = (m >> 5) & 31;
    int w  = m & 31;
    int g  = s ^ (r & 7);
    int k0 = kt * 64 + g * 8;

    const float* xb = x + (size_t)b * CIN * 1024;
    bf16x8 o;
    #pragma unroll
    for (int e = 0; e < 8; ++e) {
        int k  = k0 + e;
        int ci = k / 9;
        int r9 = k - ci * 9;
        int kh = r9 / 3;
        int kw = r9 - kh * 3;
        int hh = h + kh - 1; hh = hh < 0 ? 0 : (hh > 31 ? 31 : hh);
        int ww = w + kw - 1; ww = ww < 0 ? 0 : (ww > 31 ? 31 : ww);
        o[e] = (__bf16)xb[(ci << 10) + (hh << 5) + ww];
    }
    *(bf16x8*)(Aws + (size_t)G * 8) = o;
}

// ---- 256x128 GEMM: 4 waves of 128x64, read-first/stage-late, fused PS ----
__global__ __launch_bounds__(256, 2) void gemm_ps(
    const __bf16* __restrict__ Aws, const __bf16* __restrict__ Wws,
    const float* __restrict__ bias, float* __restrict__ out)
{
    __shared__ __align__(16) char smem[49152];  // A0:[0,16K) A1:[16K,32K) B:[32K,48K)

    // B-reuse mapping: 1216 blocks = 8 XCD * 152. Per XCD: mb in {xcd*2,
    // xcd*2+1}; nb slow -> bids 16j..16j+15 share nb's B panel.
    int bid = blockIdx.x;
    int gl  = bid >> 3;               // 0..151 within XCD
    int mb  = (bid & 7) * 2 + (gl & 1);
    int nb  = gl >> 1;                // 0..75

    int t    = threadIdx.x;
    int lane = t & 63;
    int wid  = t >> 6;
    int wm = wid >> 1, wn = wid & 1;       // 2x2 waves; wave tile 128x64

    const char* A0 = (const char*)Aws + (size_t)(mb * 2 + 0) * PANEL;
    const char* A1 = (const char*)Aws + (size_t)(mb * 2 + 1) * PANEL;
    const char* Bb = (const char*)Wws + (size_t)nb * PANEL;

    f32x4 acc[8][4] = {};
    bf16x8 af[8][2], bf[4][2];

    int rb   = lane & 15;
    int gsel = lane >> 4;      // 0..3
    int x7   = lane & 7;
    int apanel = wm << 14;     // wm*16384
    int kx0 = ((gsel    ) ^ x7) << 4;
    int kx1 = ((gsel + 4) ^ x7) << 4;

    auto stage_tile = [&](int kt) {
        const char* As0 = A0 + (size_t)kt * TB;
        const char* As1 = A1 + (size_t)kt * TB;
        const char* Bs  = Bb + (size_t)kt * TB;
        #pragma unroll
        for (int i = 0; i < 4; ++i) {
            int G16 = (i * 256 + t) * 16;
            __builtin_amdgcn_global_load_lds(
                (const __attribute__((address_space(1))) void*)(As0 + G16),
                (__attribute__((address_space(3))) void*)(smem + G16), 16, 0, 0);
            __builtin_amdgcn_global_load_lds(
                (const __attribute__((address_space(1))) void*)(As1 + G16),
                (__attribute__((address_space(3))) void*)(smem + 16384 + G16), 16, 0, 0);
            __builtin_amdgcn_global_load_lds(
                (const __attribute__((address_space(1))) void*)(Bs + G16),
                (__attribute__((address_space(3))) void*)(smem + 32768 + G16), 16, 0, 0);
        }
    };

    // prologue: stage tile 0, drain, barrier
    stage_tile(0);
    __syncthreads();     // vmcnt(0)+lgkmcnt(0) drain + barrier: tile 0 resident

    for (int kt = 0; kt < KSTEPS; ++kt) {
        int kt1 = kt + 1 < KSTEPS ? kt + 1 : KSTEPS - 1;  // harmless re-stage

        // ---- read ALL of tile kt's fragments into registers ----
        #pragma unroll
        for (int mi = 0; mi < 8; ++mi) {
            af[mi][0] = *(const bf16x8*)(smem + apanel + (mi * 16 + rb) * 128 + kx0);
            af[mi][1] = *(const bf16x8*)(smem + apanel + (mi * 16 + rb) * 128 + kx1);
        }
        #pragma unroll
        for (int ni = 0; ni < 4; ++ni) {
            bf[ni][0] = *(const bf16x8*)(smem + 32768 + ((wn * 64) + ni * 16 + rb) * 128 + kx0);
            bf[ni][1] = *(const bf16x8*)(smem + 32768 + ((wn * 64) + ni * 16 + rb) * 128 + kx1);
        }
        __syncthreads();   // lgkm drain (reads retired block-wide); vmcnt already 0

        // ---- stage tile kt+1 (overwrites buffer; safe now) ----
        stage_tile(kt1);
        SCHED0();          // pin: stage issue precedes MFMA cluster

        // ---- MFMA on registers; covers the staging latency ----
        PRIO1();
        #pragma unroll
        for (int mi = 0; mi < 8; ++mi)
            #pragma unroll
            for (int ni = 0; ni < 4; ++ni)
                acc[mi][ni] = __builtin_amdgcn_mfma_f32_16x16x32_bf16(
                    af[mi][0], bf[ni][0], acc[mi][ni], 0, 0, 0);
        #pragma unroll
        for (int mi = 0; mi < 8; ++mi)
            #pragma unroll
            for (int ni = 0; ni < 4; ++ni)
                acc[mi][ni] = __builtin_amdgcn_mfma_f32_16x16x32_bf16(
                    af[mi][1], bf[ni][1], acc[mi][ni], 0, 0, 0);
        PRIO0();

        __syncthreads();   // vmcnt(0) drain AFTER MFMA cover
    }

    // epilogue: bias + phase-shift scatter (R3/R10/R12-verified)
    int M0 = mb * 256 + wm * 128;
    int N0 = nb * 128 + wn * 64;
    int nlane = lane & 15;
    int mrow  = (lane >> 4) * 4;

    #pragma unroll
    for (int ni = 0; ni < 4; ++ni) {
        int n  = N0 + ni * 16 + nlane;
        float bv = bias[n];
        int cc  = n & 63;
        int nch = n >> 6;
        int i_hi = (cc >> 1) << 3;
        int j_hi = (cc & 1) << 7;
        #pragma unroll
        for (int mi = 0; mi < 8; ++mi) {
            #pragma unroll
            for (int r = 0; r < 4; ++r) {
                int m = M0 + mi * 16 + mrow + r;
                int b = m >> 10, h = (m >> 5) & 31, w = m & 31;
                int i = i_hi | (w & 7);
                int j = j_hi | ((h >> 1) << 3) | ((h & 1) << 2) | (w >> 3);
                out[((size_t)b * 152 + nch) * 65536 + i * 256 + j] =
                    acc[mi][ni][r] + bv;
            }
        }
    }
}

extern "C" void kernel_launch(void* const* d_in, const int* in_sizes, int n_in,
                              void* d_out, int out_size, void* d_ws, size_t ws_size,
                              hipStream_t stream) {
    const float* x    = (const float*)d_in[0];
    const float* Wt   = (const float*)d_in[1];
    const float* bias = (const float*)d_in[2];
    float* out        = (float*)d_out;

    const size_t needW = (size_t)76 * PANEL;  // 89,653,248
    const size_t needA = (size_t)32 * PANEL;  // 37,748,736

    if (ws_size >= needW + needA) {
        __bf16* Wws = (__bf16*)d_ws;
        __bf16* Aws = (__bf16*)((char*)d_ws + needW);
        pack_W<<<21888, 256, 0, stream>>>(Wt, Wws);
        pack_A<<<9216, 256, 0, stream>>>(x, Aws);
        gemm_ps<<<16 * 76, 256, 0, stream>>>(Aws, Wws, bias, out);
    } else {
        const int total = NBAT * COUT * 1024;
        conv_ps_direct<<<total / 256, 256, 0, stream>>>(x, Wt, bias, out);
    }
}

// Round 16
// 457.306 us; speedup vs baseline: 5.6443x; 1.0016x over previous
//
#include <hip/hip_runtime.h>

// Group_10: replicate-pad 3x3 conv (4,512,32,32)->(4,9728,32,32) + bias,
// then faithful-PS reinterpretation to (4,152,256,256).
//
// Round 16: R15 (best, 386us) + ONE reorder: MFMA kc0 moved BEFORE the
// mid-step barrier. Old loop serialized {24 ds_reads} then {64 MFMA}
// (LDS pipe idle during MFMA, matrix pipe idle during reads; 183us LDS +
// 177us MFMA ~ 360us serial = measured). New order lets MFMA kc0 run
// under counted lgkmcnt while kc1 reads return, and de-phases waves at
// the barrier. Reads still all precede the barrier -> stage safety
// unchanged; MFMA kc1 (+cross-block TLP) covers stage latency.

#define CIN   512
#define COUT  9728
#define NBAT  4
#define KTOT  4608
#define KSTEPS 72           // K = 72 * 64
#define TB     16384        // packed tile: 128 rows x 64 bf16 x 2B
#define PANEL  (KSTEPS * TB)

typedef __bf16 bf16x8 __attribute__((ext_vector_type(8)));
typedef float  f32x4  __attribute__((ext_vector_type(4)));

#define SCHED0() __builtin_amdgcn_sched_barrier(0)
#define PRIO1() __builtin_amdgcn_s_setprio(1)
#define PRIO0() __builtin_amdgcn_s_setprio(0)

// ---------------- fallback: direct conv (correct, slow) ----------------
__global__ __launch_bounds__(256) void conv_ps_direct(
    const float* __restrict__ x, const float* __restrict__ Wt,
    const float* __restrict__ bias, float* __restrict__ out)
{
    int flat = blockIdx.x * 256 + threadIdx.x;
    int w  = flat & 31;
    int h  = (flat >> 5) & 31;
    int t  = flat >> 10;
    int co = t % COUT;
    int b  = t / COUT;

    const float* xb = x + (size_t)b * CIN * 1024;
    const float* Wc = Wt + (size_t)co * CIN * 9;

    int hm = h > 0  ? h - 1 : 0;
    int hp = h < 31 ? h + 1 : 31;
    int wm = w > 0  ? w - 1 : 0;
    int wp = w < 31 ? w + 1 : 31;

    float acc = bias[co];
    #pragma unroll 4
    for (int ci = 0; ci < CIN; ++ci) {
        const float* xc = xb + ci * 1024;
        const float* wf = Wc + ci * 9;
        const float* r0 = xc + hm * 32;
        const float* r1 = xc + h  * 32;
        const float* r2 = xc + hp * 32;
        acc += wf[0] * r0[wm] + wf[1] * r0[w] + wf[2] * r0[wp];
        acc += wf[3] * r1[wm] + wf[4] * r1[w] + wf[5] * r1[wp];
        acc += wf[6] * r2[wm] + wf[7] * r2[w] + wf[8] * r2[wp];
    }
    int cc = co & 63;
    int n  = co >> 6;
    int i  = ((cc >> 1) << 3) | (w & 7);
    int j  = ((cc & 1) << 7) | ((h >> 1) << 3) | ((h & 1) << 2) | (w >> 3);
    out[(((size_t)b * 152 + n) * 256 + i) * 256 + j] = acc;
}

// -------- pack W: fp32 -> bf16, tiled + XOR-swizzled (R3, verified) --------
__global__ __launch_bounds__(256) void pack_W(const float* __restrict__ Wt,
                                              __bf16* __restrict__ Wws)
{
    int G = blockIdx.x * 256 + threadIdx.x;   // < 76*72*128*8
    int s    = G & 7;
    int r    = (G >> 3) & 127;
    int rest = G >> 10;                        // nb*72 + kt
    int kt = rest % KSTEPS;
    int nb = rest / KSTEPS;
    int n  = nb * 128 + r;
    int g  = s ^ (r & 7);
    int k0 = kt * 64 + g * 8;

    const float* src = Wt + (size_t)n * KTOT + k0;
    float4 v0 = *(const float4*)(src);
    float4 v1 = *(const float4*)(src + 4);
    bf16x8 o;
    o[0] = (__bf16)v0.x; o[1] = (__bf16)v0.y; o[2] = (__bf16)v0.z; o[3] = (__bf16)v0.w;
    o[4] = (__bf16)v1.x; o[5] = (__bf16)v1.y; o[6] = (__bf16)v1.z; o[7] = (__bf16)v1.w;
    *(bf16x8*)(Wws + (size_t)G * 8) = o;
}

// -------- pack A: im2col bf16, same tiling/swizzle (R3, verified) --------
__global__ __launch_bounds__(256) void pack_A(const float* __restrict__ x,
                                              __bf16* __restrict__ Aws)
{
    int G = blockIdx.x * 256 + threadIdx.x;   // < 32*72*128*8
    int s    = G & 7;
    int r    = (G >> 3) & 127;
    int rest = G >> 10;                        // mb*72 + kt
    int kt = rest % KSTEPS;
    int mb = rest / KSTEPS;
    int m  = mb * 128 + r;
    int b  = m >> 10;
    int h  = (m >> 5) & 31;
    int w  = m & 31;
    int g  = s ^ (r & 7);
    int k0 = kt * 64 + g * 8;

    const float* xb = x + (size_t)b * CIN * 1024;
    bf16x8 o;
    #pragma unroll
    for (int e = 0; e < 8; ++e) {
        int k  = k0 + e;
        int ci = k / 9;
        int r9 = k - ci * 9;
        int kh = r9 / 3;
        int kw = r9 - kh * 3;
        int hh = h + kh - 1; hh = hh < 0 ? 0 : (hh > 31 ? 31 : hh);
        int ww = w + kw - 1; ww = ww < 0 ? 0 : (ww > 31 ? 31 : ww);
        o[e] = (__bf16)xb[(ci << 10) + (hh << 5) + ww];
    }
    *(bf16x8*)(Aws + (size_t)G * 8) = o;
}

// ---- 256x128 GEMM: 4 waves of 128x64, overlapped read/MFMA, fused PS ----
__global__ __launch_bounds__(256, 2) void gemm_ps(
    const __bf16* __restrict__ Aws, const __bf16* __restrict__ Wws,
    const float* __restrict__ bias, float* __restrict__ out)
{
    __shared__ __align__(16) char smem[49152];  // A0:[0,16K) A1:[16K,32K) B:[32K,48K)

    // B-reuse mapping (R15-verified): per XCD 2 mb values; nb slow.
    int bid = blockIdx.x;
    int gl  = bid >> 3;               // 0..151 within XCD
    int mb  = (bid & 7) * 2 + (gl & 1);
    int nb  = gl >> 1;                // 0..75

    int t    = threadIdx.x;
    int lane = t & 63;
    int wid  = t >> 6;
    int wm = wid >> 1, wn = wid & 1;       // 2x2 waves; wave tile 128x64

    const char* A0 = (const char*)Aws + (size_t)(mb * 2 + 0) * PANEL;
    const char* A1 = (const char*)Aws + (size_t)(mb * 2 + 1) * PANEL;
    const char* Bb = (const char*)Wws + (size_t)nb * PANEL;

    f32x4 acc[8][4] = {};
    bf16x8 af[8][2], bf[4][2];

    int rb   = lane & 15;
    int gsel = lane >> 4;      // 0..3
    int x7   = lane & 7;
    int apanel = wm << 14;     // wm*16384
    int kx0 = ((gsel    ) ^ x7) << 4;
    int kx1 = ((gsel + 4) ^ x7) << 4;

    auto stage_tile = [&](int kt) {
        const char* As0 = A0 + (size_t)kt * TB;
        const char* As1 = A1 + (size_t)kt * TB;
        const char* Bs  = Bb + (size_t)kt * TB;
        #pragma unroll
        for (int i = 0; i < 4; ++i) {
            int G16 = (i * 256 + t) * 16;
            __builtin_amdgcn_global_load_lds(
                (const __attribute__((address_space(1))) void*)(As0 + G16),
                (__attribute__((address_space(3))) void*)(smem + G16), 16, 0, 0);
            __builtin_amdgcn_global_load_lds(
                (const __attribute__((address_space(1))) void*)(As1 + G16),
                (__attribute__((address_space(3))) void*)(smem + 16384 + G16), 16, 0, 0);
            __builtin_amdgcn_global_load_lds(
                (const __attribute__((address_space(1))) void*)(Bs + G16),
                (__attribute__((address_space(3))) void*)(smem + 32768 + G16), 16, 0, 0);
        }
    };

    // prologue: stage tile 0, drain, barrier
    stage_tile(0);
    __syncthreads();     // vmcnt(0)+lgkmcnt(0) drain + barrier: tile 0 resident

    for (int kt = 0; kt < KSTEPS; ++kt) {
        int kt1 = kt + 1 < KSTEPS ? kt + 1 : KSTEPS - 1;  // harmless re-stage

        // ---- read ALL of tile kt's fragments into registers ----
        #pragma unroll
        for (int mi = 0; mi < 8; ++mi) {
            af[mi][0] = *(const bf16x8*)(smem + apanel + (mi * 16 + rb) * 128 + kx0);
            af[mi][1] = *(const bf16x8*)(smem + apanel + (mi * 16 + rb) * 128 + kx1);
        }
        #pragma unroll
        for (int ni = 0; ni < 4; ++ni) {
            bf[ni][0] = *(const bf16x8*)(smem + 32768 + ((wn * 64) + ni * 16 + rb) * 128 + kx0);
            bf[ni][1] = *(const bf16x8*)(smem + 32768 + ((wn * 64) + ni * 16 + rb) * 128 + kx1);
        }

        // ---- MFMA kc0 BEFORE the barrier: runs under counted lgkmcnt
        // while kc1 reads return; de-phases waves at the barrier ----
        PRIO1();
        #pragma unroll
        for (int mi = 0; mi < 8; ++mi)
            #pragma unroll
            for (int ni = 0; ni < 4; ++ni)
                acc[mi][ni] = __builtin_amdgcn_mfma_f32_16x16x32_bf16(
                    af[mi][0], bf[ni][0], acc[mi][ni], 0, 0, 0);
        PRIO0();

        __syncthreads();   // all reads retired block-wide (lgkm drain)

        // ---- stage tile kt+1 (overwrites buffer; safe now) ----
        stage_tile(kt1);
        SCHED0();          // pin: stage issue precedes MFMA cluster

        // ---- MFMA kc1 covers the staging latency ----
        PRIO1();
        #pragma unroll
        for (int mi = 0; mi < 8; ++mi)
            #pragma unroll
            for (int ni = 0; ni < 4; ++ni)
                acc[mi][ni] = __builtin_amdgcn_mfma_f32_16x16x32_bf16(
                    af[mi][1], bf[ni][1], acc[mi][ni], 0, 0, 0);
        PRIO0();

        __syncthreads();   // vmcnt(0) drain AFTER MFMA cover
    }

    // epilogue: bias + phase-shift scatter (R3/R10/R12-verified)
    int M0 = mb * 256 + wm * 128;
    int N0 = nb * 128 + wn * 64;
    int nlane = lane & 15;
    int mrow  = (lane >> 4) * 4;

    #pragma unroll
    for (int ni = 0; ni < 4; ++ni) {
        int n  = N0 + ni * 16 + nlane;
        float bv = bias[n];
        int cc  = n & 63;
        int nch = n >> 6;
        int i_hi = (cc >> 1) << 3;
        int j_hi = (cc & 1) << 7;
        #pragma unroll
        for (int mi = 0; mi < 8; ++mi) {
            #pragma unroll
            for (int r = 0; r < 4; ++r) {
                int m = M0 + mi * 16 + mrow + r;
                int b = m >> 10, h = (m >> 5) & 31, w = m & 31;
                int i = i_hi | (w & 7);
                int j = j_hi | ((h >> 1) << 3) | ((h & 1) << 2) | (w >> 3);
                out[((size_t)b * 152 + nch) * 65536 + i * 256 + j] =
                    acc[mi][ni][r] + bv;
            }
        }
    }
}

extern "C" void kernel_launch(void* const* d_in, const int* in_sizes, int n_in,
                              void* d_out, int out_size, void* d_ws, size_t ws_size,
                              hipStream_t stream) {
    const float* x    = (const float*)d_in[0];
    const float* Wt   = (const float*)d_in[1];
    const float* bias = (const float*)d_in[2];
    float* out        = (float*)d_out;

    const size_t needW = (size_t)76 * PANEL;  // 89,653,248
    const size_t needA = (size_t)32 * PANEL;  // 37,748,736

    if (ws_size >= needW + needA) {
        __bf16* Wws = (__bf16*)d_ws;
        __bf16* Aws = (__bf16*)((char*)d_ws + needW);
        pack_W<<<21888, 256, 0, stream>>>(Wt, Wws);
        pack_A<<<9216, 256, 0, stream>>>(x, Aws);
        gemm_ps<<<16 * 76, 256, 0, stream>>>(Aws, Wws, bias, out);
    } else {
        const int total = NBAT * COUT * 1024;
        conv_ps_direct<<<total / 256, 256, 0, stream>>>(x, Wt, bias, out);
    }
}

// Round 17
// 453.145 us; speedup vs baseline: 5.6961x; 1.0092x over previous
//
#include <hip/hip_runtime.h>

// Group_10: replicate-pad 3x3 conv (4,512,32,32)->(4,9728,32,32) + bias,
// then faithful-PS reinterpretation to (4,152,256,256).
//
// FINAL (R15 config — best measured: gemm 386us ~950 TF, total 458us).
// Implicit GEMM M=4096 N=9728 K=4608, pre-packed bf16 operands:
//  - pack_W / pack_A: fp32->bf16, 128x64 tiles, XOR granule swizzle baked
//    into global layout (linear global_load_lds dest + swizzled ds_read).
//  - gemm_ps: 256x128 block, 4 waves of 128x64, single-buffer 48KB LDS,
//    read-first/stage-late loop (drain covered by 64-MFMA cluster, R12),
//    B-reuse XCD mapping (FETCH 740->457MB, R15), launch_bounds(256,2)
//    (VGPR 128, no spill — (256,3) spills accumulators, R14).
//  - Fused bias + phase-shift scatter epilogue (WRITE ~171MB ~ ideal).
// Ladder: 13 TF (direct) -> 762 (R3 m97-style) -> 840 (R10 geometry) ->
// 937 (R12 drain fix) -> 950 TF (R15 L2 mapping). Schedule variants
// (8-phase, B-streaming, single-wave, fat-wave, reorder) all null/negative.

#define CIN   512
#define COUT  9728
#define NBAT  4
#define KTOT  4608
#define KSTEPS 72           // K = 72 * 64
#define TB     16384        // packed tile: 128 rows x 64 bf16 x 2B
#define PANEL  (KSTEPS * TB)

typedef __bf16 bf16x8 __attribute__((ext_vector_type(8)));
typedef float  f32x4  __attribute__((ext_vector_type(4)));

#define SCHED0() __builtin_amdgcn_sched_barrier(0)
#define PRIO1() __builtin_amdgcn_s_setprio(1)
#define PRIO0() __builtin_amdgcn_s_setprio(0)

// ---------------- fallback: direct conv (correct, slow) ----------------
__global__ __launch_bounds__(256) void conv_ps_direct(
    const float* __restrict__ x, const float* __restrict__ Wt,
    const float* __restrict__ bias, float* __restrict__ out)
{
    int flat = blockIdx.x * 256 + threadIdx.x;
    int w  = flat & 31;
    int h  = (flat >> 5) & 31;
    int t  = flat >> 10;
    int co = t % COUT;
    int b  = t / COUT;

    const float* xb = x + (size_t)b * CIN * 1024;
    const float* Wc = Wt + (size_t)co * CIN * 9;

    int hm = h > 0  ? h - 1 : 0;
    int hp = h < 31 ? h + 1 : 31;
    int wm = w > 0  ? w - 1 : 0;
    int wp = w < 31 ? w + 1 : 31;

    float acc = bias[co];
    #pragma unroll 4
    for (int ci = 0; ci < CIN; ++ci) {
        const float* xc = xb + ci * 1024;
        const float* wf = Wc + ci * 9;
        const float* r0 = xc + hm * 32;
        const float* r1 = xc + h  * 32;
        const float* r2 = xc + hp * 32;
        acc += wf[0] * r0[wm] + wf[1] * r0[w] + wf[2] * r0[wp];
        acc += wf[3] * r1[wm] + wf[4] * r1[w] + wf[5] * r1[wp];
        acc += wf[6] * r2[wm] + wf[7] * r2[w] + wf[8] * r2[wp];
    }
    int cc = co & 63;
    int n  = co >> 6;
    int i  = ((cc >> 1) << 3) | (w & 7);
    int j  = ((cc & 1) << 7) | ((h >> 1) << 3) | ((h & 1) << 2) | (w >> 3);
    out[(((size_t)b * 152 + n) * 256 + i) * 256 + j] = acc;
}

// -------- pack W: fp32 -> bf16, tiled + XOR-swizzled (R3, verified) --------
__global__ __launch_bounds__(256) void pack_W(const float* __restrict__ Wt,
                                              __bf16* __restrict__ Wws)
{
    int G = blockIdx.x * 256 + threadIdx.x;   // < 76*72*128*8
    int s    = G & 7;
    int r    = (G >> 3) & 127;
    int rest = G >> 10;                        // nb*72 + kt
    int kt = rest % KSTEPS;
    int nb = rest / KSTEPS;
    int n  = nb * 128 + r;
    int g  = s ^ (r & 7);
    int k0 = kt * 64 + g * 8;

    const float* src = Wt + (size_t)n * KTOT + k0;
    float4 v0 = *(const float4*)(src);
    float4 v1 = *(const float4*)(src + 4);
    bf16x8 o;
    o[0] = (__bf16)v0.x; o[1] = (__bf16)v0.y; o[2] = (__bf16)v0.z; o[3] = (__bf16)v0.w;
    o[4] = (__bf16)v1.x; o[5] = (__bf16)v1.y; o[6] = (__bf16)v1.z; o[7] = (__bf16)v1.w;
    *(bf16x8*)(Wws + (size_t)G * 8) = o;
}

// -------- pack A: im2col bf16, same tiling/swizzle (R3, verified) --------
__global__ __launch_bounds__(256) void pack_A(const float* __restrict__ x,
                                              __bf16* __restrict__ Aws)
{
    int G = blockIdx.x * 256 + threadIdx.x;   // < 32*72*128*8
    int s    = G & 7;
    int r    = (G >> 3) & 127;
    int rest = G >> 10;                        // mb*72 + kt
    int kt = rest % KSTEPS;
    int mb = rest / KSTEPS;
    int m  = mb * 128 + r;
    int b  = m >> 10;
    int h  = (m >> 5) & 31;
    int w  = m & 31;
    int g  = s ^ (r & 7);
    int k0 = kt * 64 + g * 8;

    const float* xb = x + (size_t)b * CIN * 1024;
    bf16x8 o;
    #pragma unroll
    for (int e = 0; e < 8; ++e) {
        int k  = k0 + e;
        int ci = k / 9;
        int r9 = k - ci * 9;
        int kh = r9 / 3;
        int kw = r9 - kh * 3;
        int hh = h + kh - 1; hh = hh < 0 ? 0 : (hh > 31 ? 31 : hh);
        int ww = w + kw - 1; ww = ww < 0 ? 0 : (ww > 31 ? 31 : ww);
        o[e] = (__bf16)xb[(ci << 10) + (hh << 5) + ww];
    }
    *(bf16x8*)(Aws + (size_t)G * 8) = o;
}

// ---- 256x128 GEMM: 4 waves of 128x64, read-first/stage-late, fused PS ----
__global__ __launch_bounds__(256, 2) void gemm_ps(
    const __bf16* __restrict__ Aws, const __bf16* __restrict__ Wws,
    const float* __restrict__ bias, float* __restrict__ out)
{
    __shared__ __align__(16) char smem[49152];  // A0:[0,16K) A1:[16K,32K) B:[32K,48K)

    // B-reuse mapping (R15-verified): per XCD 2 mb values (A panels pinned
    // in XCD L2); nb slow -> bids 16j..16j+15 share nb's B panel.
    int bid = blockIdx.x;
    int gl  = bid >> 3;               // 0..151 within XCD
    int mb  = (bid & 7) * 2 + (gl & 1);
    int nb  = gl >> 1;                // 0..75

    int t    = threadIdx.x;
    int lane = t & 63;
    int wid  = t >> 6;
    int wm = wid >> 1, wn = wid & 1;       // 2x2 waves; wave tile 128x64

    const char* A0 = (const char*)Aws + (size_t)(mb * 2 + 0) * PANEL;
    const char* A1 = (const char*)Aws + (size_t)(mb * 2 + 1) * PANEL;
    const char* Bb = (const char*)Wws + (size_t)nb * PANEL;

    f32x4 acc[8][4] = {};
    bf16x8 af[8][2], bf[4][2];

    int rb   = lane & 15;
    int gsel = lane >> 4;      // 0..3
    int x7   = lane & 7;
    int apanel = wm << 14;     // wm*16384
    int kx0 = ((gsel    ) ^ x7) << 4;
    int kx1 = ((gsel + 4) ^ x7) << 4;

    auto stage_tile = [&](int kt) {
        const char* As0 = A0 + (size_t)kt * TB;
        const char* As1 = A1 + (size_t)kt * TB;
        const char* Bs  = Bb + (size_t)kt * TB;
        #pragma unroll
        for (int i = 0; i < 4; ++i) {
            int G16 = (i * 256 + t) * 16;
            __builtin_amdgcn_global_load_lds(
                (const __attribute__((address_space(1))) void*)(As0 + G16),
                (__attribute__((address_space(3))) void*)(smem + G16), 16, 0, 0);
            __builtin_amdgcn_global_load_lds(
                (const __attribute__((address_space(1))) void*)(As1 + G16),
                (__attribute__((address_space(3))) void*)(smem + 16384 + G16), 16, 0, 0);
            __builtin_amdgcn_global_load_lds(
                (const __attribute__((address_space(1))) void*)(Bs + G16),
                (__attribute__((address_space(3))) void*)(smem + 32768 + G16), 16, 0, 0);
        }
    };

    // prologue: stage tile 0, drain, barrier
    stage_tile(0);
    __syncthreads();     // vmcnt(0)+lgkmcnt(0) drain + barrier: tile 0 resident

    for (int kt = 0; kt < KSTEPS; ++kt) {
        int kt1 = kt + 1 < KSTEPS ? kt + 1 : KSTEPS - 1;  // harmless re-stage

        // ---- read ALL of tile kt's fragments into registers ----
        #pragma unroll
        for (int mi = 0; mi < 8; ++mi) {
            af[mi][0] = *(const bf16x8*)(smem + apanel + (mi * 16 + rb) * 128 + kx0);
            af[mi][1] = *(const bf16x8*)(smem + apanel + (mi * 16 + rb) * 128 + kx1);
        }
        #pragma unroll
        for (int ni = 0; ni < 4; ++ni) {
            bf[ni][0] = *(const bf16x8*)(smem + 32768 + ((wn * 64) + ni * 16 + rb) * 128 + kx0);
            bf[ni][1] = *(const bf16x8*)(smem + 32768 + ((wn * 64) + ni * 16 + rb) * 128 + kx1);
        }
        __syncthreads();   // lgkm drain (reads retired block-wide); vmcnt already 0

        // ---- stage tile kt+1 (overwrites buffer; safe now) ----
        stage_tile(kt1);
        SCHED0();          // pin: stage issue precedes MFMA cluster

        // ---- MFMA on registers; covers the staging latency ----
        PRIO1();
        #pragma unroll
        for (int mi = 0; mi < 8; ++mi)
            #pragma unroll
            for (int ni = 0; ni < 4; ++ni)
                acc[mi][ni] = __builtin_amdgcn_mfma_f32_16x16x32_bf16(
                    af[mi][0], bf[ni][0], acc[mi][ni], 0, 0, 0);
        #pragma unroll
        for (int mi = 0; mi < 8; ++mi)
            #pragma unroll
            for (int ni = 0; ni < 4; ++ni)
                acc[mi][ni] = __builtin_amdgcn_mfma_f32_16x16x32_bf16(
                    af[mi][1], bf[ni][1], acc[mi][ni], 0, 0, 0);
        PRIO0();

        __syncthreads();   // vmcnt(0) drain AFTER MFMA cover
    }

    // epilogue: bias + phase-shift scatter (R3/R10/R12-verified)
    int M0 = mb * 256 + wm * 128;
    int N0 = nb * 128 + wn * 64;
    int nlane = lane & 15;
    int mrow  = (lane >> 4) * 4;

    #pragma unroll
    for (int ni = 0; ni < 4; ++ni) {
        int n  = N0 + ni * 16 + nlane;
        float bv = bias[n];
        int cc  = n & 63;
        int nch = n >> 6;
        int i_hi = (cc >> 1) << 3;
        int j_hi = (cc & 1) << 7;
        #pragma unroll
        for (int mi = 0; mi < 8; ++mi) {
            #pragma unroll
            for (int r = 0; r < 4; ++r) {
                int m = M0 + mi * 16 + mrow + r;
                int b = m >> 10, h = (m >> 5) & 31, w = m & 31;
                int i = i_hi | (w & 7);
                int j = j_hi | ((h >> 1) << 3) | ((h & 1) << 2) | (w >> 3);
                out[((size_t)b * 152 + nch) * 65536 + i * 256 + j] =
                    acc[mi][ni][r] + bv;
            }
        }
    }
}

extern "C" void kernel_launch(void* const* d_in, const int* in_sizes, int n_in,
                              void* d_out, int out_size, void* d_ws, size_t ws_size,
                              hipStream_t stream) {
    const float* x    = (const float*)d_in[0];
    const float* Wt   = (const float*)d_in[1];
    const float* bias = (const float*)d_in[2];
    float* out        = (float*)d_out;

    const size_t needW = (size_t)76 * PANEL;  // 89,653,248
    const size_t needA = (size_t)32 * PANEL;  // 37,748,736

    if (ws_size >= needW + needA) {
        __bf16* Wws = (__bf16*)d_ws;
        __bf16* Aws = (__bf16*)((char*)d_ws + needW);
        pack_W<<<21888, 256, 0, stream>>>(Wt, Wws);
        pack_A<<<9216, 256, 0, stream>>>(x, Aws);
        gemm_ps<<<16 * 76, 256, 0, stream>>>(Aws, Wws, bias, out);
    } else {
        const int total = NBAT * COUT * 1024;
        conv_ps_direct<<<total / 256, 256, 0, stream>>>(x, Wt, bias, out);
    }
}